// Round 5
// baseline (270.326 us; speedup 1.0000x reference)
//
#include <hip/hip_runtime.h>
#include <hip/hip_bf16.h>

// SerializedEmbedding: out[b,s,:] = weight[indices[b,s], :]
// indices: (8, 2048) int -> 16384 tokens
// weight:  (50304, 1024) fp32
// out:     (8, 2048, 1024) fp32
//
// 8 tokens per 256-thread block: each wave (64 lanes) handles 2 tokens,
// each lane issues 2 independent float4 loads per token (4 loads in
// flight per lane total) before any store waits -> latency-tolerant,
// coalesced on both gather-read and write.

#define EMB_DIM     1024
#define V4_PER_ROW  (EMB_DIM / 4)   // 256 float4 per row
#define TOKS_BLOCK  8               // tokens per block
#define TOKS_WAVE   2               // tokens per wave

__global__ __launch_bounds__(256) void SerializedEmbedding_7121055777167_kernel(
    const int* __restrict__ indices,
    const float* __restrict__ weight,
    float* __restrict__ out,
    int num_tokens)
{
    const int wave = threadIdx.x >> 6;   // 0..3
    const int lane = threadIdx.x & 63;

    const int t0 = blockIdx.x * TOKS_BLOCK + wave * TOKS_WAVE;
    const int t1 = t0 + 1;

    // Wave-uniform index loads (scalar-broadcast).
    const int row0 = (t0 < num_tokens) ? indices[t0] : 0;
    const int row1 = (t1 < num_tokens) ? indices[t1] : 0;

    const float4* __restrict__ s0 =
        reinterpret_cast<const float4*>(weight + (size_t)row0 * EMB_DIM);
    const float4* __restrict__ s1 =
        reinterpret_cast<const float4*>(weight + (size_t)row1 * EMB_DIM);

    // 4 independent loads in flight per lane.
    float4 a0 = s0[lane];
    float4 a1 = s0[lane + 64];
    float4 a2 = s0[lane + 128];
    float4 a3 = s0[lane + 192];
    float4 b0 = s1[lane];
    float4 b1 = s1[lane + 64];
    float4 b2 = s1[lane + 128];
    float4 b3 = s1[lane + 192];

    if (t0 < num_tokens) {
        float4* __restrict__ d0 =
            reinterpret_cast<float4*>(out + (size_t)t0 * EMB_DIM);
        d0[lane]       = a0;
        d0[lane + 64]  = a1;
        d0[lane + 128] = a2;
        d0[lane + 192] = a3;
    }
    if (t1 < num_tokens) {
        float4* __restrict__ d1 =
            reinterpret_cast<float4*>(out + (size_t)t1 * EMB_DIM);
        d1[lane]       = b0;
        d1[lane + 64]  = b1;
        d1[lane + 128] = b2;
        d1[lane + 192] = b3;
    }
}

extern "C" void kernel_launch(void* const* d_in, const int* in_sizes, int n_in,
                              void* d_out, int out_size, void* d_ws, size_t ws_size,
                              hipStream_t stream)
{
    const int*   indices = (const int*)d_in[0];
    const float* weight  = (const float*)d_in[1];
    float*       out     = (float*)d_out;

    const int num_tokens = in_sizes[0];  // 8 * 2048 = 16384

    dim3 grid((num_tokens + TOKS_BLOCK - 1) / TOKS_BLOCK);  // 2048
    dim3 block(256);

    SerializedEmbedding_7121055777167_kernel<<<grid, block, 0, stream>>>(
        indices, weight, out, num_tokens);
}